// Round 16
// baseline (331.433 us; speedup 1.0000x reference)
//
#include <hip/hip_runtime.h>
#include <hip/hip_bf16.h>

// N=16384 queries, C=1024 classes, D=4096.
// sims = l2norm(hvs) @ l2norm(am)^T ; preds = argmax ; eta = (sims[:,1]-sims[:,0])/4 + 0.5
// R16: norm_all restructured as wave-per-row (no LDS reduce, no syncthreads,
// 16 in-flight 16B loads/lane) to reach the HBM BW floor. gemm1 / finalizeA /
// recheck identical to R15 (327.7us, all-passed).

#define NQ 16384
#define NC 1024
#define DK 4096
#define TAU 4e-4f
#define WLMAX 16384

typedef __attribute__((ext_vector_type(8))) short short8;
typedef __attribute__((ext_vector_type(4))) float f32x4;
typedef unsigned short ushort_t;

__device__ __forceinline__ unsigned short bf16_rne(float x) {
    unsigned int u = __float_as_uint(x);
    u += 0x7FFFu + ((u >> 16) & 1u);
    return (unsigned short)(u >> 16);
}

#define GLDS(g, l)                                                                       \
    __builtin_amdgcn_global_load_lds((const __attribute__((address_space(1))) void*)(g), \
                                     (__attribute__((address_space(3))) void*)(l), 16, 0, 0)

// ---------------- fused row-norm + normalize + bf16-hi split, wave-per-row ----------------
// 4 rows per 256-thread block; each wave owns one row end-to-end.
__global__ void __launch_bounds__(256) norm_all_kernel(const float* __restrict__ hvs,
                                                       const float* __restrict__ am,
                                                       ushort_t* __restrict__ Ah,
                                                       ushort_t* __restrict__ Bh,
                                                       float* __restrict__ arn) {
    const int lane = threadIdx.x & 63;
    const int wv = threadIdx.x >> 6;
    const int b = blockIdx.x * 4 + wv;  // row over [am | hvs]
    const float* x;
    ushort_t* hp;
    if (b < NC) {
        x = am + (size_t)b * DK;
        hp = Bh + (size_t)b * DK;
    } else {
        const int r = b - NC;
        x = hvs + (size_t)r * DK;
        hp = Ah + (size_t)r * DK;
    }
    const float4* x4 = (const float4*)x;

    float4 v[16];
    float ss = 0.f;
#pragma unroll
    for (int i = 0; i < 16; ++i) {
        v[i] = x4[lane + i * 64];
        ss += v[i].x * v[i].x + v[i].y * v[i].y + v[i].z * v[i].z + v[i].w * v[i].w;
    }
#pragma unroll
    for (int off = 32; off; off >>= 1) ss += __shfl_xor(ss, off, 64);
    const float r = 1.0f / fmaxf(sqrtf(ss), 1e-8f);
    if (b < NC && lane == 0) arn[b] = r;

#pragma unroll
    for (int i = 0; i < 16; ++i) {
        const unsigned short h0 = bf16_rne(v[i].x * r);
        const unsigned short h1 = bf16_rne(v[i].y * r);
        const unsigned short h2 = bf16_rne(v[i].z * r);
        const unsigned short h3 = bf16_rne(v[i].w * r);
        *(uint2*)(hp + (size_t)(lane + i * 64) * 4) =
            make_uint2((unsigned)h0 | ((unsigned)h1 << 16), (unsigned)h2 | ((unsigned)h3 << 16));
    }
}

// ---------------- pass 1: 1-term bf16 GEMM, m97 structure, fused top-2 (with i2) ----------------
__global__ void __launch_bounds__(256, 3) gemm1_kernel(const ushort_t* __restrict__ Ah,
                                                       const ushort_t* __restrict__ Bh,
                                                       float4* __restrict__ cand,
                                                       float* __restrict__ s01) {
    __shared__ __align__(16) ushort_t lA[2][128 * 32];  // 16 KB
    __shared__ __align__(16) ushort_t lB[2][128 * 32];  // 16 KB

    const int tid = threadIdx.x;
    const int lane = tid & 63;
    const int w = tid >> 6;   // 0..3
    const int wm = w >> 1;    // 0..1
    const int wn = w & 1;     // 0..1

    // XCD swizzle: each XCD owns 16 consecutive by-panels (x all 8 bx)
    const int id = blockIdx.x;              // 0..1023
    const int xcd = id & 7;
    const int slot = id >> 3;               // 0..127
    const int by = xcd * 16 + (slot >> 3);  // 0..127
    const int bx = slot & 7;                // 0..7

    // staging: per operand tile = 128 rows x 4 slots(16B) = 512 chunks; 2/thread
    int sq[2];
    size_t offA[2], offB[2];
#pragma unroll
    for (int i = 0; i < 2; ++i) {
        const int q = tid + i * 256;
        sq[i] = q;
        const int row = q >> 2;
        const int gs = (q & 3) ^ ((row >> 1) & 3);  // R3-proven swizzle
        offA[i] = (size_t)(by * 128 + row) * DK + gs * 8;
        offB[i] = (size_t)(bx * 128 + row) * DK + gs * 8;
    }

    f32x4 acc[4][4];
#pragma unroll
    for (int m = 0; m < 4; ++m)
#pragma unroll
        for (int n = 0; n < 4; ++n) acc[m][n] = (f32x4){0.f, 0.f, 0.f, 0.f};

    const int r0 = lane & 15;
    const int rg = lane >> 4;

    int aoff[4], boff[4];
#pragma unroll
    for (int m = 0; m < 4; ++m) {
        const int row = wm * 64 + m * 16 + r0;
        aoff[m] = row * 32 + (rg ^ ((row >> 1) & 3)) * 8;
    }
#pragma unroll
    for (int n = 0; n < 4; ++n) {
        const int col = wn * 64 + n * 16 + r0;
        boff[n] = col * 32 + (rg ^ ((col >> 1) & 3)) * 8;
    }

    auto stage = [&](int buf, int kt) {
        const size_t ko = (size_t)kt * 32;
        GLDS(Ah + offA[0] + ko, &lA[buf][sq[0] * 8]);
        GLDS(Ah + offA[1] + ko, &lA[buf][sq[1] * 8]);
        GLDS(Bh + offB[0] + ko, &lB[buf][sq[0] * 8]);
        GLDS(Bh + offB[1] + ko, &lB[buf][sq[1] * 8]);
    };

    stage(0, 0);
    const int nK = DK / 32;  // 128
    for (int kt = 0; kt < nK; ++kt) {
        const int cur = kt & 1;
        if (kt + 1 < nK) {
            stage(cur ^ 1, kt + 1);                           // 4 new loads in flight
            asm volatile("s_waitcnt vmcnt(4)" ::: "memory");  // cur's 4 done
        } else {
            asm volatile("s_waitcnt vmcnt(0)" ::: "memory");
        }
        __builtin_amdgcn_s_barrier();

        short8 b0 = *(const short8*)&lB[cur][boff[0]];
        short8 b1 = *(const short8*)&lB[cur][boff[1]];
        short8 b2 = *(const short8*)&lB[cur][boff[2]];
        short8 b3 = *(const short8*)&lB[cur][boff[3]];
        short8 a0 = *(const short8*)&lA[cur][aoff[0]];
        short8 a1 = *(const short8*)&lA[cur][aoff[1]];
        short8 a2 = *(const short8*)&lA[cur][aoff[2]];
        short8 a3 = *(const short8*)&lA[cur][aoff[3]];
        asm volatile("s_waitcnt lgkmcnt(0)" ::: "memory");
        __builtin_amdgcn_s_setprio(1);
        acc[0][0] = __builtin_amdgcn_mfma_f32_16x16x32_bf16(a0, b0, acc[0][0], 0, 0, 0);
        acc[0][1] = __builtin_amdgcn_mfma_f32_16x16x32_bf16(a0, b1, acc[0][1], 0, 0, 0);
        acc[0][2] = __builtin_amdgcn_mfma_f32_16x16x32_bf16(a0, b2, acc[0][2], 0, 0, 0);
        acc[0][3] = __builtin_amdgcn_mfma_f32_16x16x32_bf16(a0, b3, acc[0][3], 0, 0, 0);
        acc[1][0] = __builtin_amdgcn_mfma_f32_16x16x32_bf16(a1, b0, acc[1][0], 0, 0, 0);
        acc[1][1] = __builtin_amdgcn_mfma_f32_16x16x32_bf16(a1, b1, acc[1][1], 0, 0, 0);
        acc[1][2] = __builtin_amdgcn_mfma_f32_16x16x32_bf16(a1, b2, acc[1][2], 0, 0, 0);
        acc[1][3] = __builtin_amdgcn_mfma_f32_16x16x32_bf16(a1, b3, acc[1][3], 0, 0, 0);
        acc[2][0] = __builtin_amdgcn_mfma_f32_16x16x32_bf16(a2, b0, acc[2][0], 0, 0, 0);
        acc[2][1] = __builtin_amdgcn_mfma_f32_16x16x32_bf16(a2, b1, acc[2][1], 0, 0, 0);
        acc[2][2] = __builtin_amdgcn_mfma_f32_16x16x32_bf16(a2, b2, acc[2][2], 0, 0, 0);
        acc[2][3] = __builtin_amdgcn_mfma_f32_16x16x32_bf16(a2, b3, acc[2][3], 0, 0, 0);
        acc[3][0] = __builtin_amdgcn_mfma_f32_16x16x32_bf16(a3, b0, acc[3][0], 0, 0, 0);
        acc[3][1] = __builtin_amdgcn_mfma_f32_16x16x32_bf16(a3, b1, acc[3][1], 0, 0, 0);
        acc[3][2] = __builtin_amdgcn_mfma_f32_16x16x32_bf16(a3, b2, acc[3][2], 0, 0, 0);
        acc[3][3] = __builtin_amdgcn_mfma_f32_16x16x32_bf16(a3, b3, acc[3][3], 0, 0, 0);
        __builtin_amdgcn_s_setprio(0);
        __builtin_amdgcn_s_barrier();
    }

    // epilogue: C/D layout col=lane&15, row=(lane>>4)*4+j [m89]; per-strip top-2
    // WITH indices. 16 col-strips of 64: strip = bx*2 + wn (ascending col order).
    const int rowb = by * 128 + wm * 64;
#pragma unroll
    for (int m = 0; m < 4; ++m) {
#pragma unroll
        for (int j = 0; j < 4; ++j) {
            float v1 = acc[m][0][j];
            int i1 = bx * 128 + wn * 64 + r0;
            float v2 = -3.402823466e+38f;
            int i2 = i1;
#pragma unroll
            for (int n = 1; n < 4; ++n) {
                const float v = acc[m][n][j];
                const int c = bx * 128 + wn * 64 + n * 16 + r0;
                if (v > v1) { v2 = v1; i2 = i1; v1 = v; i1 = c; }
                else if (v > v2) { v2 = v; i2 = c; }
            }
#pragma unroll
            for (int off = 1; off < 16; off <<= 1) {
                const float o1 = __shfl_xor(v1, off, 64);
                const float o2 = __shfl_xor(v2, off, 64);
                const int oi1 = __shfl_xor(i1, off, 64);
                const int oi2 = __shfl_xor(i2, off, 64);
                if (o1 > v1 || (o1 == v1 && oi1 < i1)) {
                    const float pv = v1; const int pi = i1;
                    v1 = o1; i1 = oi1;
                    if (pv >= o2) { v2 = pv; i2 = pi; }
                    else { v2 = o2; i2 = oi2; }
                } else {
                    if (o1 >= v2) { v2 = o1; i2 = oi1; }
                }
            }
            const int row = rowb + m * 16 + rg * 4 + j;
            if (r0 == 0)
                cand[(size_t)row * 16 + bx * 2 + wn] = make_float4(v1, (float)i1, v2, (float)i2);
            if (bx == 0 && wn == 0 && r0 < 2) s01[row * 2 + r0] = acc[m][0][j];
        }
    }
}

// ---------------- finalize pass 1: merge strips, write pred/eta, flag close rows ----------------
__global__ void __launch_bounds__(256) finalizeA_kernel(const float4* __restrict__ cand,
                                                        const float* __restrict__ s01,
                                                        float* __restrict__ out,
                                                        int* __restrict__ wl,
                                                        int* __restrict__ wc) {
    const int row = blockIdx.x * 256 + threadIdx.x;
    const float4* c = cand + (size_t)row * 16;
    float4 c0 = c[0];
    float M = c0.x, iM = c0.y, M2 = c0.z;
#pragma unroll
    for (int k = 1; k < 16; ++k) {
        const float4 ck = c[k];
        if (ck.x > M) { M2 = fmaxf(M, ck.z); M = ck.x; iM = ck.y; }
        else { M2 = fmaxf(M2, ck.x); }
    }
    out[row] = iM;
    out[NQ + row] = (s01[row * 2 + 1] - s01[row * 2 + 0]) * 0.25f + 0.5f;
    if (M - M2 < TAU) {
        const int p = atomicAdd(wc, 1);
        if (p < WLMAX) wl[p] = row;
    }
}

// ---------------- exact-f32 candidate recheck for flagged rows ----------------
// One block per flagged row; wave w owns strips [4w,4w+4). Strip with v2 >=
// wnd: scan ALL its 64 classes (complete: a class >= wnd missed by top-2
// forces v2 >= wnd in its strip). Other strips: check top-1 if >= wnd.
// 4-class-ILP dots (64 loads in flight).
__global__ void __launch_bounds__(256) recheck_kernel(const float* __restrict__ hvs,
                                                      const float* __restrict__ am,
                                                      const float* __restrict__ arn,
                                                      const float4* __restrict__ cand,
                                                      const int* __restrict__ wl,
                                                      const int* __restrict__ wc,
                                                      float* __restrict__ out) {
    const int cnt = min(*wc, WLMAX);
    const int s = blockIdx.x;
    if (s >= cnt) return;
    const int row = wl[s];
    const int tid = threadIdx.x;
    const int lane = tid & 63;
    const int w = tid >> 6;

    __shared__ __align__(16) float aLDS[DK];  // raw hvs row (16 KB, 1024 float4)
    __shared__ float4 cLDS[16];
    __shared__ float wsum[4];
    __shared__ float wbest[4];
    __shared__ int wbidx[4];

    if (tid < 16) cLDS[tid] = cand[(size_t)row * 16 + tid];

    // load hvs row, compute 1/norm, stage raw row into LDS
    const float4* x4 = (const float4*)(hvs + (size_t)row * DK);
    float4 v[4];
    float ss = 0.f;
#pragma unroll
    for (int i = 0; i < 4; ++i) {
        v[i] = x4[tid * 4 + i];
        ss += v[i].x * v[i].x + v[i].y * v[i].y + v[i].z * v[i].z + v[i].w * v[i].w;
    }
#pragma unroll
    for (int off = 32; off; off >>= 1) ss += __shfl_xor(ss, off, 64);
    if (lane == 0) wsum[w] = ss;
#pragma unroll
    for (int i = 0; i < 4; ++i) ((float4*)aLDS)[tid * 4 + i] = v[i];
    __syncthreads();
    const float rinv = 1.0f / fmaxf(sqrtf(wsum[0] + wsum[1] + wsum[2] + wsum[3]), 1e-8f);

    // window (block-uniform)
    float M = cLDS[0].x;
#pragma unroll
    for (int k = 1; k < 16; ++k) M = fmaxf(M, cLDS[k].x);
    const float wnd = M - TAU;

    const float4* am4 = (const float4*)am;
    const float4* a4 = (const float4*)aLDS;

    float best = -3.402823466e+38f;
    int bidx = 0x7FFFFFFF;

    auto exact1 = [&](int c) {  // one class
        float p = 0.f;
#pragma unroll
        for (int j = 0; j < 16; ++j) {
            const float4 av = a4[j * 64 + lane];
            const float4 bv = am4[(size_t)c * (DK / 4) + j * 64 + lane];
            p += av.x * bv.x + av.y * bv.y + av.z * bv.z + av.w * bv.w;
        }
#pragma unroll
        for (int off = 32; off; off >>= 1) p += __shfl_xor(p, off, 64);
        if (lane == 0) {
            const float sim = p * rinv * arn[c];
            if (sim > best || (sim == best && c < bidx)) { best = sim; bidx = c; }
        }
    };
    auto exact4 = [&](int c0) {  // classes c0..c0+3, 4-way ILP
        float p0 = 0.f, p1 = 0.f, p2 = 0.f, p3 = 0.f;
#pragma unroll
        for (int j = 0; j < 16; ++j) {
            const float4 av = a4[j * 64 + lane];
            const float4 b0 = am4[(size_t)(c0 + 0) * (DK / 4) + j * 64 + lane];
            const float4 b1 = am4[(size_t)(c0 + 1) * (DK / 4) + j * 64 + lane];
            const float4 b2 = am4[(size_t)(c0 + 2) * (DK / 4) + j * 64 + lane];
            const float4 b3 = am4[(size_t)(c0 + 3) * (DK / 4) + j * 64 + lane];
            p0 += av.x * b0.x + av.y * b0.y + av.z * b0.z + av.w * b0.w;
            p1 += av.x * b1.x + av.y * b1.y + av.z * b1.z + av.w * b1.w;
            p2 += av.x * b2.x + av.y * b2.y + av.z * b2.z + av.w * b2.w;
            p3 += av.x * b3.x + av.y * b3.y + av.z * b3.z + av.w * b3.w;
        }
        float pp[4] = {p0, p1, p2, p3};
#pragma unroll
        for (int q = 0; q < 4; ++q) {
            float p = pp[q];
#pragma unroll
            for (int off = 32; off; off >>= 1) p += __shfl_xor(p, off, 64);
            if (lane == 0) {
                const int c = c0 + q;
                const float sim = p * rinv * arn[c];
                if (sim > best || (sim == best && c < bidx)) { best = sim; bidx = c; }
            }
        }
    };

    // wave w: strips 4w..4w+3
    for (int k = 4 * w; k < 4 * w + 4; ++k) {
        const float4 ck = cLDS[k];
        if (ck.z >= wnd) {
            // strip's v2 in window: scan all 64 classes (covers i1,i2 too)
            for (int g = 0; g < 16; ++g) exact4(k * 64 + g * 4);
        } else if (ck.x >= wnd) {
            exact1((int)ck.y);
        }
    }

    if (lane == 0) { wbest[w] = best; wbidx[w] = bidx; }
    __syncthreads();
    if (tid == 0) {
        float b = wbest[0];
        int bi = wbidx[0];
#pragma unroll
        for (int k = 1; k < 4; ++k) {
            if (wbest[k] > b || (wbest[k] == b && wbidx[k] < bi)) { b = wbest[k]; bi = wbidx[k]; }
        }
        out[row] = (float)bi;
    }
}

extern "C" void kernel_launch(void* const* d_in, const int* in_sizes, int n_in,
                              void* d_out, int out_size, void* d_ws, size_t ws_size,
                              hipStream_t stream) {
    const float* hvs = (const float*)d_in[0];  // [16384,4096] f32
    const float* am  = (const float*)d_in[1];  // [1024,4096] f32
    float* out = (float*)d_out;                // [preds | eta]

    ushort_t* Bh = (ushort_t*)d_ws;                     // 8 MB
    ushort_t* Ah = Bh + (size_t)NC * DK;                // 128 MB
    float4* cand = (float4*)(Ah + (size_t)NQ * DK);     // 4 MB
    float* s01 = (float*)(cand + (size_t)NQ * 16);      // 128 KB
    float* arn = s01 + (size_t)NQ * 2;                  // 4 KB
    int* wl = (int*)(arn + NC);                         // 64 KB
    int* wc = wl + WLMAX;                               // 4 B

    hipMemsetAsync(wc, 0, sizeof(int), stream);
    norm_all_kernel<<<(NC + NQ) / 4, 256, 0, stream>>>(hvs, am, Ah, Bh, arn);
    gemm1_kernel<<<1024, 256, 0, stream>>>(Ah, Bh, cand, s01);
    finalizeA_kernel<<<NQ / 256, 256, 0, stream>>>(cand, s01, out, wl, wc);
    recheck_kernel<<<WLMAX, 256, 0, stream>>>(hvs, am, arn, cand, wl, wc, out);
}

// Round 17
// 327.701 us; speedup vs baseline: 1.0114x; 1.0114x over previous
//
#include <hip/hip_runtime.h>
#include <hip/hip_bf16.h>

// N=16384 queries, C=1024 classes, D=4096.
// sims = l2norm(hvs) @ l2norm(am)^T ; preds = argmax ; eta = (sims[:,1]-sims[:,0])/4 + 0.5
// R17 = R15 champion config (327.7us), locking in: block-per-row norm_all
// (R16's wave-per-row variant was neutral-negative), m97-structure 1-term bf16
// gemm1 with fused per-strip top-2, rank-2-window exact-f32 recheck.

#define NQ 16384
#define NC 1024
#define DK 4096
#define TAU 4e-4f
#define WLMAX 16384

typedef __attribute__((ext_vector_type(8))) short short8;
typedef __attribute__((ext_vector_type(4))) float f32x4;
typedef unsigned short ushort_t;

__device__ __forceinline__ unsigned short bf16_rne(float x) {
    unsigned int u = __float_as_uint(x);
    u += 0x7FFFu + ((u >> 16) & 1u);
    return (unsigned short)(u >> 16);
}

#define GLDS(g, l)                                                                       \
    __builtin_amdgcn_global_load_lds((const __attribute__((address_space(1))) void*)(g), \
                                     (__attribute__((address_space(3))) void*)(l), 16, 0, 0)

// ---------------- fused row-norm + normalize + bf16-hi split, both inputs ----------------
__global__ void __launch_bounds__(256) norm_all_kernel(const float* __restrict__ hvs,
                                                       const float* __restrict__ am,
                                                       ushort_t* __restrict__ Ah,
                                                       ushort_t* __restrict__ Bh,
                                                       float* __restrict__ arn) {
    const int b = blockIdx.x;
    const int tid = threadIdx.x;
    const float* x;
    ushort_t* hp;
    if (b < NC) {
        x = am + (size_t)b * DK;
        hp = Bh + (size_t)b * DK;
    } else {
        const int r = b - NC;
        x = hvs + (size_t)r * DK;
        hp = Ah + (size_t)r * DK;
    }
    const float4* x4 = (const float4*)x;

    float4 v[4];
    float ss = 0.f;
#pragma unroll
    for (int i = 0; i < 4; ++i) {
        v[i] = x4[tid * 4 + i];
        ss += v[i].x * v[i].x + v[i].y * v[i].y + v[i].z * v[i].z + v[i].w * v[i].w;
    }
#pragma unroll
    for (int off = 32; off; off >>= 1) ss += __shfl_xor(ss, off, 64);
    __shared__ float wsum[4];
    const int lane = tid & 63, w = tid >> 6;
    if (lane == 0) wsum[w] = ss;
    __syncthreads();
    const float tot = wsum[0] + wsum[1] + wsum[2] + wsum[3];
    const float r = 1.0f / fmaxf(sqrtf(tot), 1e-8f);
    if (b < NC && tid == 0) arn[b] = r;

    ushort_t hbuf[16];
#pragma unroll
    for (int i = 0; i < 4; ++i) {
        const float xs[4] = {v[i].x * r, v[i].y * r, v[i].z * r, v[i].w * r};
#pragma unroll
        for (int j = 0; j < 4; ++j) hbuf[i * 4 + j] = bf16_rne(xs[j]);
    }
    ushort_t* hq = hp + tid * 16;
    *(short8*)hq = *(short8*)hbuf;
    *(short8*)(hq + 8) = *(short8*)(hbuf + 8);
}

// ---------------- pass 1: 1-term bf16 GEMM, m97 structure, fused top-2 (with i2) ----------------
__global__ void __launch_bounds__(256, 3) gemm1_kernel(const ushort_t* __restrict__ Ah,
                                                       const ushort_t* __restrict__ Bh,
                                                       float4* __restrict__ cand,
                                                       float* __restrict__ s01) {
    __shared__ __align__(16) ushort_t lA[2][128 * 32];  // 16 KB
    __shared__ __align__(16) ushort_t lB[2][128 * 32];  // 16 KB

    const int tid = threadIdx.x;
    const int lane = tid & 63;
    const int w = tid >> 6;   // 0..3
    const int wm = w >> 1;    // 0..1
    const int wn = w & 1;     // 0..1

    // XCD swizzle: each XCD owns 16 consecutive by-panels (x all 8 bx)
    const int id = blockIdx.x;              // 0..1023
    const int xcd = id & 7;
    const int slot = id >> 3;               // 0..127
    const int by = xcd * 16 + (slot >> 3);  // 0..127
    const int bx = slot & 7;                // 0..7

    // staging: per operand tile = 128 rows x 4 slots(16B) = 512 chunks; 2/thread
    int sq[2];
    size_t offA[2], offB[2];
#pragma unroll
    for (int i = 0; i < 2; ++i) {
        const int q = tid + i * 256;
        sq[i] = q;
        const int row = q >> 2;
        const int gs = (q & 3) ^ ((row >> 1) & 3);  // R3-proven swizzle
        offA[i] = (size_t)(by * 128 + row) * DK + gs * 8;
        offB[i] = (size_t)(bx * 128 + row) * DK + gs * 8;
    }

    f32x4 acc[4][4];
#pragma unroll
    for (int m = 0; m < 4; ++m)
#pragma unroll
        for (int n = 0; n < 4; ++n) acc[m][n] = (f32x4){0.f, 0.f, 0.f, 0.f};

    const int r0 = lane & 15;
    const int rg = lane >> 4;

    int aoff[4], boff[4];
#pragma unroll
    for (int m = 0; m < 4; ++m) {
        const int row = wm * 64 + m * 16 + r0;
        aoff[m] = row * 32 + (rg ^ ((row >> 1) & 3)) * 8;
    }
#pragma unroll
    for (int n = 0; n < 4; ++n) {
        const int col = wn * 64 + n * 16 + r0;
        boff[n] = col * 32 + (rg ^ ((col >> 1) & 3)) * 8;
    }

    auto stage = [&](int buf, int kt) {
        const size_t ko = (size_t)kt * 32;
        GLDS(Ah + offA[0] + ko, &lA[buf][sq[0] * 8]);
        GLDS(Ah + offA[1] + ko, &lA[buf][sq[1] * 8]);
        GLDS(Bh + offB[0] + ko, &lB[buf][sq[0] * 8]);
        GLDS(Bh + offB[1] + ko, &lB[buf][sq[1] * 8]);
    };

    stage(0, 0);
    const int nK = DK / 32;  // 128
    for (int kt = 0; kt < nK; ++kt) {
        const int cur = kt & 1;
        if (kt + 1 < nK) {
            stage(cur ^ 1, kt + 1);                           // 4 new loads in flight
            asm volatile("s_waitcnt vmcnt(4)" ::: "memory");  // cur's 4 done
        } else {
            asm volatile("s_waitcnt vmcnt(0)" ::: "memory");
        }
        __builtin_amdgcn_s_barrier();

        short8 b0 = *(const short8*)&lB[cur][boff[0]];
        short8 b1 = *(const short8*)&lB[cur][boff[1]];
        short8 b2 = *(const short8*)&lB[cur][boff[2]];
        short8 b3 = *(const short8*)&lB[cur][boff[3]];
        short8 a0 = *(const short8*)&lA[cur][aoff[0]];
        short8 a1 = *(const short8*)&lA[cur][aoff[1]];
        short8 a2 = *(const short8*)&lA[cur][aoff[2]];
        short8 a3 = *(const short8*)&lA[cur][aoff[3]];
        asm volatile("s_waitcnt lgkmcnt(0)" ::: "memory");
        __builtin_amdgcn_s_setprio(1);
        acc[0][0] = __builtin_amdgcn_mfma_f32_16x16x32_bf16(a0, b0, acc[0][0], 0, 0, 0);
        acc[0][1] = __builtin_amdgcn_mfma_f32_16x16x32_bf16(a0, b1, acc[0][1], 0, 0, 0);
        acc[0][2] = __builtin_amdgcn_mfma_f32_16x16x32_bf16(a0, b2, acc[0][2], 0, 0, 0);
        acc[0][3] = __builtin_amdgcn_mfma_f32_16x16x32_bf16(a0, b3, acc[0][3], 0, 0, 0);
        acc[1][0] = __builtin_amdgcn_mfma_f32_16x16x32_bf16(a1, b0, acc[1][0], 0, 0, 0);
        acc[1][1] = __builtin_amdgcn_mfma_f32_16x16x32_bf16(a1, b1, acc[1][1], 0, 0, 0);
        acc[1][2] = __builtin_amdgcn_mfma_f32_16x16x32_bf16(a1, b2, acc[1][2], 0, 0, 0);
        acc[1][3] = __builtin_amdgcn_mfma_f32_16x16x32_bf16(a1, b3, acc[1][3], 0, 0, 0);
        acc[2][0] = __builtin_amdgcn_mfma_f32_16x16x32_bf16(a2, b0, acc[2][0], 0, 0, 0);
        acc[2][1] = __builtin_amdgcn_mfma_f32_16x16x32_bf16(a2, b1, acc[2][1], 0, 0, 0);
        acc[2][2] = __builtin_amdgcn_mfma_f32_16x16x32_bf16(a2, b2, acc[2][2], 0, 0, 0);
        acc[2][3] = __builtin_amdgcn_mfma_f32_16x16x32_bf16(a2, b3, acc[2][3], 0, 0, 0);
        acc[3][0] = __builtin_amdgcn_mfma_f32_16x16x32_bf16(a3, b0, acc[3][0], 0, 0, 0);
        acc[3][1] = __builtin_amdgcn_mfma_f32_16x16x32_bf16(a3, b1, acc[3][1], 0, 0, 0);
        acc[3][2] = __builtin_amdgcn_mfma_f32_16x16x32_bf16(a3, b2, acc[3][2], 0, 0, 0);
        acc[3][3] = __builtin_amdgcn_mfma_f32_16x16x32_bf16(a3, b3, acc[3][3], 0, 0, 0);
        __builtin_amdgcn_s_setprio(0);
        __builtin_amdgcn_s_barrier();
    }

    // epilogue: C/D layout col=lane&15, row=(lane>>4)*4+j [m89]; per-strip top-2
    // WITH indices. 16 col-strips of 64: strip = bx*2 + wn (ascending col order).
    const int rowb = by * 128 + wm * 64;
#pragma unroll
    for (int m = 0; m < 4; ++m) {
#pragma unroll
        for (int j = 0; j < 4; ++j) {
            float v1 = acc[m][0][j];
            int i1 = bx * 128 + wn * 64 + r0;
            float v2 = -3.402823466e+38f;
            int i2 = i1;
#pragma unroll
            for (int n = 1; n < 4; ++n) {
                const float v = acc[m][n][j];
                const int c = bx * 128 + wn * 64 + n * 16 + r0;
                if (v > v1) { v2 = v1; i2 = i1; v1 = v; i1 = c; }
                else if (v > v2) { v2 = v; i2 = c; }
            }
#pragma unroll
            for (int off = 1; off < 16; off <<= 1) {
                const float o1 = __shfl_xor(v1, off, 64);
                const float o2 = __shfl_xor(v2, off, 64);
                const int oi1 = __shfl_xor(i1, off, 64);
                const int oi2 = __shfl_xor(i2, off, 64);
                if (o1 > v1 || (o1 == v1 && oi1 < i1)) {
                    const float pv = v1; const int pi = i1;
                    v1 = o1; i1 = oi1;
                    if (pv >= o2) { v2 = pv; i2 = pi; }
                    else { v2 = o2; i2 = oi2; }
                } else {
                    if (o1 >= v2) { v2 = o1; i2 = oi1; }
                }
            }
            const int row = rowb + m * 16 + rg * 4 + j;
            if (r0 == 0)
                cand[(size_t)row * 16 + bx * 2 + wn] = make_float4(v1, (float)i1, v2, (float)i2);
            if (bx == 0 && wn == 0 && r0 < 2) s01[row * 2 + r0] = acc[m][0][j];
        }
    }
}

// ---------------- finalize pass 1: merge strips, write pred/eta, flag close rows ----------------
__global__ void __launch_bounds__(256) finalizeA_kernel(const float4* __restrict__ cand,
                                                        const float* __restrict__ s01,
                                                        float* __restrict__ out,
                                                        int* __restrict__ wl,
                                                        int* __restrict__ wc) {
    const int row = blockIdx.x * 256 + threadIdx.x;
    const float4* c = cand + (size_t)row * 16;
    float4 c0 = c[0];
    float M = c0.x, iM = c0.y, M2 = c0.z;
#pragma unroll
    for (int k = 1; k < 16; ++k) {
        const float4 ck = c[k];
        if (ck.x > M) { M2 = fmaxf(M, ck.z); M = ck.x; iM = ck.y; }
        else { M2 = fmaxf(M2, ck.x); }
    }
    out[row] = iM;
    out[NQ + row] = (s01[row * 2 + 1] - s01[row * 2 + 0]) * 0.25f + 0.5f;
    if (M - M2 < TAU) {
        const int p = atomicAdd(wc, 1);
        if (p < WLMAX) wl[p] = row;
    }
}

// ---------------- exact-f32 candidate recheck for flagged rows ----------------
// One block per flagged row; wave w owns strips [4w,4w+4). Strip with v2 >=
// wnd: scan ALL its 64 classes (complete: a class >= wnd missed by top-2
// forces v2 >= wnd in its strip). Other strips: check top-1 if >= wnd.
// 4-class-ILP dots (64 loads in flight).
__global__ void __launch_bounds__(256) recheck_kernel(const float* __restrict__ hvs,
                                                      const float* __restrict__ am,
                                                      const float* __restrict__ arn,
                                                      const float4* __restrict__ cand,
                                                      const int* __restrict__ wl,
                                                      const int* __restrict__ wc,
                                                      float* __restrict__ out) {
    const int cnt = min(*wc, WLMAX);
    const int s = blockIdx.x;
    if (s >= cnt) return;
    const int row = wl[s];
    const int tid = threadIdx.x;
    const int lane = tid & 63;
    const int w = tid >> 6;

    __shared__ __align__(16) float aLDS[DK];  // raw hvs row (16 KB, 1024 float4)
    __shared__ float4 cLDS[16];
    __shared__ float wsum[4];
    __shared__ float wbest[4];
    __shared__ int wbidx[4];

    if (tid < 16) cLDS[tid] = cand[(size_t)row * 16 + tid];

    // load hvs row, compute 1/norm, stage raw row into LDS
    const float4* x4 = (const float4*)(hvs + (size_t)row * DK);
    float4 v[4];
    float ss = 0.f;
#pragma unroll
    for (int i = 0; i < 4; ++i) {
        v[i] = x4[tid * 4 + i];
        ss += v[i].x * v[i].x + v[i].y * v[i].y + v[i].z * v[i].z + v[i].w * v[i].w;
    }
#pragma unroll
    for (int off = 32; off; off >>= 1) ss += __shfl_xor(ss, off, 64);
    if (lane == 0) wsum[w] = ss;
#pragma unroll
    for (int i = 0; i < 4; ++i) ((float4*)aLDS)[tid * 4 + i] = v[i];
    __syncthreads();
    const float rinv = 1.0f / fmaxf(sqrtf(wsum[0] + wsum[1] + wsum[2] + wsum[3]), 1e-8f);

    // window (block-uniform)
    float M = cLDS[0].x;
#pragma unroll
    for (int k = 1; k < 16; ++k) M = fmaxf(M, cLDS[k].x);
    const float wnd = M - TAU;

    const float4* am4 = (const float4*)am;
    const float4* a4 = (const float4*)aLDS;

    float best = -3.402823466e+38f;
    int bidx = 0x7FFFFFFF;

    auto exact1 = [&](int c) {  // one class
        float p = 0.f;
#pragma unroll
        for (int j = 0; j < 16; ++j) {
            const float4 av = a4[j * 64 + lane];
            const float4 bv = am4[(size_t)c * (DK / 4) + j * 64 + lane];
            p += av.x * bv.x + av.y * bv.y + av.z * bv.z + av.w * bv.w;
        }
#pragma unroll
        for (int off = 32; off; off >>= 1) p += __shfl_xor(p, off, 64);
        if (lane == 0) {
            const float sim = p * rinv * arn[c];
            if (sim > best || (sim == best && c < bidx)) { best = sim; bidx = c; }
        }
    };
    auto exact4 = [&](int c0) {  // classes c0..c0+3, 4-way ILP
        float p0 = 0.f, p1 = 0.f, p2 = 0.f, p3 = 0.f;
#pragma unroll
        for (int j = 0; j < 16; ++j) {
            const float4 av = a4[j * 64 + lane];
            const float4 b0 = am4[(size_t)(c0 + 0) * (DK / 4) + j * 64 + lane];
            const float4 b1 = am4[(size_t)(c0 + 1) * (DK / 4) + j * 64 + lane];
            const float4 b2 = am4[(size_t)(c0 + 2) * (DK / 4) + j * 64 + lane];
            const float4 b3 = am4[(size_t)(c0 + 3) * (DK / 4) + j * 64 + lane];
            p0 += av.x * b0.x + av.y * b0.y + av.z * b0.z + av.w * b0.w;
            p1 += av.x * b1.x + av.y * b1.y + av.z * b1.z + av.w * b1.w;
            p2 += av.x * b2.x + av.y * b2.y + av.z * b2.z + av.w * b2.w;
            p3 += av.x * b3.x + av.y * b3.y + av.z * b3.z + av.w * b3.w;
        }
        float pp[4] = {p0, p1, p2, p3};
#pragma unroll
        for (int q = 0; q < 4; ++q) {
            float p = pp[q];
#pragma unroll
            for (int off = 32; off; off >>= 1) p += __shfl_xor(p, off, 64);
            if (lane == 0) {
                const int c = c0 + q;
                const float sim = p * rinv * arn[c];
                if (sim > best || (sim == best && c < bidx)) { best = sim; bidx = c; }
            }
        }
    };

    // wave w: strips 4w..4w+3
    for (int k = 4 * w; k < 4 * w + 4; ++k) {
        const float4 ck = cLDS[k];
        if (ck.z >= wnd) {
            // strip's v2 in window: scan all 64 classes (covers i1,i2 too)
            for (int g = 0; g < 16; ++g) exact4(k * 64 + g * 4);
        } else if (ck.x >= wnd) {
            exact1((int)ck.y);
        }
    }

    if (lane == 0) { wbest[w] = best; wbidx[w] = bidx; }
    __syncthreads();
    if (tid == 0) {
        float b = wbest[0];
        int bi = wbidx[0];
#pragma unroll
        for (int k = 1; k < 4; ++k) {
            if (wbest[k] > b || (wbest[k] == b && wbidx[k] < bi)) { b = wbest[k]; bi = wbidx[k]; }
        }
        out[row] = (float)bi;
    }
}

extern "C" void kernel_launch(void* const* d_in, const int* in_sizes, int n_in,
                              void* d_out, int out_size, void* d_ws, size_t ws_size,
                              hipStream_t stream) {
    const float* hvs = (const float*)d_in[0];  // [16384,4096] f32
    const float* am  = (const float*)d_in[1];  // [1024,4096] f32
    float* out = (float*)d_out;                // [preds | eta]

    ushort_t* Bh = (ushort_t*)d_ws;                     // 8 MB
    ushort_t* Ah = Bh + (size_t)NC * DK;                // 128 MB
    float4* cand = (float4*)(Ah + (size_t)NQ * DK);     // 4 MB
    float* s01 = (float*)(cand + (size_t)NQ * 16);      // 128 KB
    float* arn = s01 + (size_t)NQ * 2;                  // 4 KB
    int* wl = (int*)(arn + NC);                         // 64 KB
    int* wc = wl + WLMAX;                               // 4 B

    hipMemsetAsync(wc, 0, sizeof(int), stream);
    norm_all_kernel<<<NC + NQ, 256, 0, stream>>>(hvs, am, Ah, Bh, arn);
    gemm1_kernel<<<1024, 256, 0, stream>>>(Ah, Bh, cand, s01);
    finalizeA_kernel<<<NQ / 256, 256, 0, stream>>>(cand, s01, out, wl, wc);
    recheck_kernel<<<WLMAX, 256, 0, stream>>>(hvs, am, arn, cand, wl, wc, out);
}